// Round 9
// baseline (1224.912 us; speedup 1.0000x reference)
//
#include <hip/hip_runtime.h>
#include <hip/hip_bf16.h>

#define DIM 384
#define HEADS 12
#define NTOK 49
#define TOKENS 3137
#define M_ATTN 100352   // 32*64*49 window rows
#define M_FULL 100384   // 32*3137 token rows
#define M_PAD  100480   // 785*128
#define SCALEQ 0.17677669529663687f

typedef __attribute__((ext_vector_type(8))) short s8v;
typedef __attribute__((ext_vector_type(4))) float f4v;
typedef unsigned short u16;

__device__ __forceinline__ float b2f(int s) {
  union { unsigned u; float f; } c; c.u = ((unsigned)(s & 0xffff)) << 16; return c.f;
}
__device__ __forceinline__ u16 f2b(float f) {
  __hip_bfloat16 h = __float2bfloat16(f);
  return *reinterpret_cast<u16*>(&h);
}
__device__ __forceinline__ void gload16(const void* g, void* l) {
  __builtin_amdgcn_global_load_lds((const __attribute__((address_space(1))) void*)g,
                                   (__attribute__((address_space(3))) void*)l, 16, 0, 0);
}
__device__ __forceinline__ float gelu_f(float val) {
  float u = __builtin_fmaf(0.0713548163f * val, val * val, 1.5957691216f * val);
  return val * __builtin_amdgcn_rcpf(1.0f + __expf(-u));
}
// tiled+pre-swizzled layout [tile][ks][128 rows][64 cols]
__device__ __forceinline__ size_t tidx(int tile, int KS, int rl, int c) {
  return ((size_t)(tile * KS + (c >> 6)) * 128 + rl) * 64
       + (((((c >> 3) & 7)) ^ (rl & 7)) << 3) + (c & 7);
}

// ---------------- weight convert ----------------
__global__ void k_convert(const float* __restrict__ qkv_w, const float* __restrict__ qkv_b,
                          const float* __restrict__ proj_w, const float* __restrict__ fc1_w,
                          const float* __restrict__ fc2_w,
                          u16* __restrict__ wt_qkv, float* __restrict__ qkvb_s,
                          u16* __restrict__ wt_proj, u16* __restrict__ wt_fc1,
                          u16* __restrict__ wt_fc2) {
  int i = blockIdx.x * 256 + threadIdx.x;
  if (i < 1152 * 384) { int n = i / 384, k = i % 384;
    float v = qkv_w[(size_t)k * 1152 + n]; if (n < 384) v *= SCALEQ;
    wt_qkv[tidx(n >> 7, 6, n & 127, k)] = f2b(v); }
  if (i < 1152) qkvb_s[i] = qkv_b[i] * (i < 384 ? SCALEQ : 1.0f);
  if (i < 384 * 384) { int n = i / 384, k = i % 384;
    wt_proj[tidx(n >> 7, 6, n & 127, k)] = f2b(proj_w[(size_t)k * 384 + n]); }
  if (i < 1536 * 384) { int n = i / 384, k = i % 384;
    wt_fc1[tidx(n >> 7, 6, n & 127, k)] = f2b(fc1_w[(size_t)k * 1536 + n]); }
  if (i < 384 * 1536) { int n = i / 1536, k = i % 1536;
    wt_fc2[tidx(n >> 7, 24, n & 127, k)] = f2b(fc2_w[(size_t)k * 384 + n]); }
}

// ---------------- ADD table ----------------
__global__ void k_addtab(const float* __restrict__ rpb, float* __restrict__ ADD) {
  int idx = blockIdx.x * 256 + threadIdx.x;
  if (idx >= 4 * HEADS * NTOK * NTOK) return;
  int j = idx % NTOK, t = idx / NTOK;
  int i = t % NTOK; t /= NTOK;
  int h = t % HEADS; int cls = t / HEADS;
  int ii = i / 7, jj = i % 7, ji = j / 7, j2 = j % 7;
  int rpi = (ii - ji + 6) * 13 + (jj - j2 + 6);
  float v = rpb[rpi * HEADS + h];
  int rh = (cls & 2) ? (ii < 4 ? 1 : 2) : 0;
  int rw = (cls & 1) ? (jj < 4 ? 1 : 2) : 0;
  int sh = (cls & 2) ? (ji < 4 ? 1 : 2) : 0;
  int sw = (cls & 1) ? (j2 < 4 ? 1 : 2) : 0;
  if (rh != sh || rw != sw) v -= 100.0f;
  ADD[idx] = v;
}

// ---------------- LN1 -> XW tiled ----------------
__global__ void k_ln1(const float* __restrict__ x, const float* __restrict__ g,
                      const float* __restrict__ b, u16* __restrict__ xwt, int t0) {
  int wid = threadIdx.x >> 6, lane = threadIdx.x & 63;
  int ml = blockIdx.x * 4 + wid;
  int t = t0 + ml;
  int bi = t / 3136, rem = t % 3136;
  int win = rem / NTOK, n = rem % NTOK;
  int wh = win >> 3, ww = win & 7, ii = n / 7, jj = n % 7;
  int h = (wh * 7 + ii + 3) % 56;
  int w = (ww * 7 + jj + 3) % 56;
  const float* src = x + ((size_t)bi * TOKENS + 1 + h * 56 + w) * DIM;
  float v[6];
  #pragma unroll
  for (int e = 0; e < 6; e++) v[e] = src[lane + e * 64];
  float s = v[0] + v[1] + v[2] + v[3] + v[4] + v[5];
  #pragma unroll
  for (int m = 1; m < 64; m <<= 1) s += __shfl_xor(s, m);
  float mu = s * (1.0f / 384.0f);
  float q = 0.f;
  #pragma unroll
  for (int e = 0; e < 6; e++) { float d = v[e] - mu; q += d * d; }
  #pragma unroll
  for (int m = 1; m < 64; m <<= 1) q += __shfl_xor(q, m);
  float rstd = rsqrtf(q * (1.0f / 384.0f) + 1e-5f);
  int tile = ml >> 7, rl = ml & 127;
  #pragma unroll
  for (int e = 0; e < 6; e++) {
    int c = lane + e * 64;
    xwt[tidx(tile, 6, rl, c)] = f2b((v[e] - mu) * rstd * g[c] + b[c]);
  }
}

// ---------------- bf16 MFMA GEMM (round-8, unchanged) ----------------
template<int MODE>
__global__ __launch_bounds__(256) void k_gemm(
    const u16* __restrict__ At, const u16* __restrict__ Bt,
    const float* __restrict__ bias, u16* __restrict__ Cb,
    float* __restrict__ outp, const u16* __restrict__ residt,
    int N, int KT, int row_off) {
  __shared__ __align__(16) u16 As[2][128 * 64];
  __shared__ __align__(16) u16 Bs[2][128 * 64];
  int gx = gridDim.x;
  int lid = blockIdx.y * gx + blockIdx.x;
  int nwg = gx * gridDim.y;
  int q = nwg >> 3, r = nwg & 7;
  int xcd = lid & 7, loc = lid >> 3;
  int tile = (xcd < r ? xcd * (q + 1) : r * (q + 1) + (xcd - r) * q) + loc;
  int m0 = (tile / gx) * 128, n0 = (tile % gx) * 128;
  int t = threadIdx.x;
  int lane = t & 63, wave = t >> 6;
  int lo = lane & 15, hi = lane >> 4;
  int wr = (wave >> 1) * 64, wc = (wave & 1) * 64;
  const u16* Ag = At + ((size_t)(m0 >> 7) * KT) * 8192 + wave * 2048 + lane * 8;
  const u16* Bg = Bt + ((size_t)(n0 >> 7) * KT) * 8192 + wave * 2048 + lane * 8;
  f4v acc[4][4];
  #pragma unroll
  for (int m = 0; m < 4; m++)
    #pragma unroll
    for (int n = 0; n < 4; n++) acc[m][n] = (f4v)(0.0f);
#define STAGE(buf, kt) do {                                              \
    u16* al_ = As[buf] + wave * 2048;                                    \
    u16* bl_ = Bs[buf] + wave * 2048;                                    \
    _Pragma("unroll")                                                    \
    for (int g_ = 0; g_ < 4; g_++) {                                     \
      gload16(Ag + (size_t)(kt) * 8192 + g_ * 512, al_ + g_ * 512);      \
      gload16(Bg + (size_t)(kt) * 8192 + g_ * 512, bl_ + g_ * 512);      \
    } } while (0)
  STAGE(0, 0);
  for (int kt = 0; kt < KT; ++kt) {
    int c = kt & 1;
    if (kt + 1 < KT) {
      STAGE(1 - c, kt + 1);
      asm volatile("s_waitcnt vmcnt(8)" ::: "memory");
    } else {
      asm volatile("s_waitcnt vmcnt(0)" ::: "memory");
    }
    __builtin_amdgcn_s_barrier();
    __builtin_amdgcn_sched_barrier(0);
    s8v af[2][4], bfr[2][4];
    #pragma unroll
    for (int kk = 0; kk < 2; kk++) {
      #pragma unroll
      for (int m = 0; m < 4; m++) {
        int row = wr + m * 16 + lo;
        af[kk][m] = *(const s8v*)(As[c] + row * 64 + (((kk * 4 + hi) ^ (row & 7)) * 8));
      }
      #pragma unroll
      for (int n = 0; n < 4; n++) {
        int row = wc + n * 16 + lo;
        bfr[kk][n] = *(const s8v*)(Bs[c] + row * 64 + (((kk * 4 + hi) ^ (row & 7)) * 8));
      }
    }
    asm volatile("s_waitcnt lgkmcnt(0)" ::: "memory");
    __builtin_amdgcn_sched_barrier(0);
    __builtin_amdgcn_s_barrier();
    __builtin_amdgcn_sched_barrier(0);
    __builtin_amdgcn_s_setprio(1);
    #pragma unroll
    for (int kk = 0; kk < 2; kk++)
      #pragma unroll
      for (int m = 0; m < 4; m++)
        #pragma unroll
        for (int n = 0; n < 4; n++)
          acc[m][n] = __builtin_amdgcn_mfma_f32_16x16x32_bf16(af[kk][m], bfr[kk][n], acc[m][n], 0, 0, 0);
    __builtin_amdgcn_s_setprio(0);
  }
#undef STAGE
  #pragma unroll
  for (int m = 0; m < 4; m++) {
    #pragma unroll
    for (int n = 0; n < 4; n++) {
      int gcol = n0 + wc + n * 16 + lo;
      float bv = bias[gcol];
      #pragma unroll
      for (int r2 = 0; r2 < 4; r2++) {
        int lrow = wr + m * 16 + hi * 4 + r2;
        float val = acc[m][n][r2] + bv;
        if (MODE == 0) {
          Cb[(size_t)(m0 + lrow) * N + gcol] = f2b(val);
        } else if (MODE == 1) {
          Cb[tidx(m0 >> 7, 24, lrow, gcol)] = f2b(gelu_f(val));
        } else {
          int orow = m0 + lrow + row_off;
          if (orow < M_FULL) {
            float res = b2f(residt[tidx(orow >> 7, 6, orow & 127, gcol)]);
            outp[(size_t)orow * 384 + gcol] = val + res;
          }
        }
      }
    }
  }
}

// ---------------- DIAGNOSTIC kernels: fc1-shaped GEMM, K-loop repeated 16x.
// ABL=1: stage-only (loads + vmcnt + barriers). ABL=2: compute-only (ds_read+MFMA+barriers).
// Output goes to scratch that the real pipeline overwrites afterwards.
template<int ABL>
__global__ __launch_bounds__(256) void k_diag(
    const u16* __restrict__ At, const u16* __restrict__ Bt,
    const float* __restrict__ bias, u16* __restrict__ Cb, int N, int KT) {
  __shared__ __align__(16) u16 As[2][128 * 64];
  __shared__ __align__(16) u16 Bs[2][128 * 64];
  int gx = gridDim.x;
  int lid = blockIdx.y * gx + blockIdx.x;
  int nwg = gx * gridDim.y;
  int q = nwg >> 3, r = nwg & 7;
  int xcd = lid & 7, loc = lid >> 3;
  int tile = (xcd < r ? xcd * (q + 1) : r * (q + 1) + (xcd - r) * q) + loc;
  int m0 = (tile / gx) * 128, n0 = (tile % gx) * 128;
  int t = threadIdx.x;
  int lane = t & 63, wave = t >> 6;
  int lo = lane & 15, hi = lane >> 4;
  int wr = (wave >> 1) * 64, wc = (wave & 1) * 64;
  const u16* Ag = At + ((size_t)(m0 >> 7) * KT) * 8192 + wave * 2048 + lane * 8;
  const u16* Bg = Bt + ((size_t)(n0 >> 7) * KT) * 8192 + wave * 2048 + lane * 8;
  f4v acc[4][4];
  #pragma unroll
  for (int m = 0; m < 4; m++)
    #pragma unroll
    for (int n = 0; n < 4; n++) acc[m][n] = (f4v)(0.0f);
#define STAGE(buf, kt) do {                                              \
    u16* al_ = As[buf] + wave * 2048;                                    \
    u16* bl_ = Bs[buf] + wave * 2048;                                    \
    _Pragma("unroll")                                                    \
    for (int g_ = 0; g_ < 4; g_++) {                                     \
      gload16(Ag + (size_t)(kt) * 8192 + g_ * 512, al_ + g_ * 512);      \
      gload16(Bg + (size_t)(kt) * 8192 + g_ * 512, bl_ + g_ * 512);      \
    } } while (0)
  for (int rep = 0; rep < 16; rep++) {
    if (ABL == 1) {
      STAGE(0, 0);
      for (int kt = 0; kt < KT; ++kt) {
        int c = kt & 1;
        if (kt + 1 < KT) {
          STAGE(1 - c, kt + 1);
          asm volatile("s_waitcnt vmcnt(8)" ::: "memory");
        } else {
          asm volatile("s_waitcnt vmcnt(0)" ::: "memory");
        }
        __builtin_amdgcn_s_barrier();
        __builtin_amdgcn_sched_barrier(0);
        __builtin_amdgcn_s_barrier();
      }
    } else {
      for (int kt = 0; kt < KT; ++kt) {
        int c = kt & 1;
        __builtin_amdgcn_s_barrier();
        __builtin_amdgcn_sched_barrier(0);
        s8v af[2][4], bfr[2][4];
        #pragma unroll
        for (int kk = 0; kk < 2; kk++) {
          #pragma unroll
          for (int m = 0; m < 4; m++) {
            int row = wr + m * 16 + lo;
            af[kk][m] = *(const s8v*)(As[c] + row * 64 + (((kk * 4 + hi) ^ (row & 7)) * 8));
          }
          #pragma unroll
          for (int n = 0; n < 4; n++) {
            int row = wc + n * 16 + lo;
            bfr[kk][n] = *(const s8v*)(Bs[c] + row * 64 + (((kk * 4 + hi) ^ (row & 7)) * 8));
          }
        }
        asm volatile("s_waitcnt lgkmcnt(0)" ::: "memory");
        __builtin_amdgcn_sched_barrier(0);
        __builtin_amdgcn_s_barrier();
        __builtin_amdgcn_sched_barrier(0);
        __builtin_amdgcn_s_setprio(1);
        #pragma unroll
        for (int kk = 0; kk < 2; kk++)
          #pragma unroll
          for (int m = 0; m < 4; m++)
            #pragma unroll
            for (int n = 0; n < 4; n++)
              acc[m][n] = __builtin_amdgcn_mfma_f32_16x16x32_bf16(af[kk][m], bfr[kk][n], acc[m][n], 0, 0, 0);
        __builtin_amdgcn_s_setprio(0);
      }
    }
  }
#undef STAGE
  // epilogue keeps everything live; writes scratch (overwritten by real fc1/proj later)
  #pragma unroll
  for (int m = 0; m < 4; m++)
    #pragma unroll
    for (int n = 0; n < 4; n++) {
      int gcol = n0 + wc + n * 16 + lo;
      float bv = bias[gcol];
      #pragma unroll
      for (int r2 = 0; r2 < 4; r2++) {
        int lrow = wr + m * 16 + hi * 4 + r2;
        Cb[tidx(m0 >> 7, 24, lrow, gcol)] = f2b(gelu_f(acc[m][n][r2] + bv));
      }
    }
}

// ---------------- MFMA attention (round-8, unchanged) ----------------
__global__ __launch_bounds__(256) void k_attn2(const u16* __restrict__ qkv,
                                               const float* __restrict__ ADD,
                                               u16* __restrict__ aot, int win0) {
  __shared__ u16 PT[4][64][76];
  __shared__ u16 VT[4][32][76];
  int wid = threadIdx.x >> 6, lane = threadIdx.x & 63;
  int lo = lane & 15, hi = lane >> 4;
  int gw = blockIdx.x * 4 + wid;
  int win_l = gw / HEADS, h = gw % HEADS;
  int nw = (win0 + win_l) & 63;
  int wh = nw >> 3, ww = nw & 7;
  int cls = ((wh == 7) ? 2 : 0) + ((ww == 7) ? 1 : 0);
  size_t rowbase = (size_t)win_l * NTOK;
  u16 (*pt)[76] = PT[wid];
  u16 (*vt)[76] = VT[wid];

  int rcl[4];
  #pragma unroll
  for (int ti = 0; ti < 4; ti++) {
    int r = ti * 16 + lo;
    rcl[ti] = r < NTOK ? r : NTOK - 1;
  }
  int jrow = lane < NTOK ? lane : NTOK - 1;

  s8v af[4], bf[4];
  #pragma unroll
  for (int ti = 0; ti < 4; ti++) {
    af[ti] = *(const s8v*)(qkv + (rowbase + rcl[ti]) * 1152 + h * 32 + hi * 8);
    bf[ti] = *(const s8v*)(qkv + (rowbase + rcl[ti]) * 1152 + 384 + h * 32 + hi * 8);
  }
  f4v st[4][4];
  #pragma unroll
  for (int mi = 0; mi < 4; mi++)
    #pragma unroll
    for (int ni = 0; ni < 4; ni++)
      st[mi][ni] = __builtin_amdgcn_mfma_f32_16x16x32_bf16(af[mi], bf[ni], (f4v)(0.0f), 0, 0, 0);

  {
    const u16* vsrc = qkv + (rowbase + jrow) * 1152 + 768 + h * 32;
    #pragma unroll
    for (int d0 = 0; d0 < 32; d0 += 8) {
      s8v v = *(const s8v*)(vsrc + d0);
      #pragma unroll
      for (int e = 0; e < 8; e++) vt[d0 + e][lane] = (u16)v[e];
    }
  }

  const float* addb = ADD + ((size_t)cls * HEADS + h) * (NTOK * NTOK);
  #pragma unroll
  for (int mi = 0; mi < 4; mi++)
    #pragma unroll
    for (int ni = 0; ni < 4; ni++) {
      int jj = ni * 16 + lo;
      #pragma unroll
      for (int r = 0; r < 4; r++) {
        int i = mi * 16 + hi * 4 + r;
        if (jj < NTOK) {
          int ic = i < NTOK ? i : NTOK - 1;
          st[mi][ni][r] += addb[ic * NTOK + jj];
        } else st[mi][ni][r] = -1e30f;
      }
    }

  float invl[4][4];
  #pragma unroll
  for (int mi = 0; mi < 4; mi++)
    #pragma unroll
    for (int r = 0; r < 4; r++) {
      float m = fmaxf(fmaxf(st[mi][0][r], st[mi][1][r]), fmaxf(st[mi][2][r], st[mi][3][r]));
      #pragma unroll
      for (int msk = 1; msk < 16; msk <<= 1) m = fmaxf(m, __shfl_xor(m, msk));
      float s = 0.f;
      #pragma unroll
      for (int ni = 0; ni < 4; ni++) {
        float p = __expf(st[mi][ni][r] - m);
        st[mi][ni][r] = p;
        s += p;
      }
      #pragma unroll
      for (int msk = 1; msk < 16; msk <<= 1) s += __shfl_xor(s, msk);
      invl[mi][r] = 1.0f / s;
    }

  #pragma unroll
  for (int ni = 0; ni < 4; ni++)
    #pragma unroll
    for (int mi = 0; mi < 4; mi++) {
      ushort4 pk;
      pk.x = f2b(st[mi][ni][0]); pk.y = f2b(st[mi][ni][1]);
      pk.z = f2b(st[mi][ni][2]); pk.w = f2b(st[mi][ni][3]);
      *(ushort4*)(&pt[ni * 16 + lo][mi * 16 + hi * 4]) = pk;
    }

  f4v ot[4][2];
  #pragma unroll
  for (int mi = 0; mi < 4; mi++)
    #pragma unroll
    for (int dt = 0; dt < 2; dt++) ot[mi][dt] = (f4v)(0.0f);
  #pragma unroll
  for (int kt = 0; kt < 2; kt++) {
    s8v pa[4], vb[2];
    #pragma unroll
    for (int mi = 0; mi < 4; mi++) {
      s8v p;
      #pragma unroll
      for (int e = 0; e < 8; e++) p[e] = (short)pt[kt * 32 + hi * 8 + e][mi * 16 + lo];
      pa[mi] = p;
    }
    #pragma unroll
    for (int dt = 0; dt < 2; dt++) {
      short4 a = *(const short4*)(&vt[dt * 16 + lo][kt * 32 + hi * 8]);
      short4 b = *(const short4*)(&vt[dt * 16 + lo][kt * 32 + hi * 8 + 4]);
      s8v v; v[0] = a.x; v[1] = a.y; v[2] = a.z; v[3] = a.w;
             v[4] = b.x; v[5] = b.y; v[6] = b.z; v[7] = b.w;
      vb[dt] = v;
    }
    #pragma unroll
    for (int mi = 0; mi < 4; mi++)
      #pragma unroll
      for (int dt = 0; dt < 2; dt++)
        ot[mi][dt] = __builtin_amdgcn_mfma_f32_16x16x32_bf16(pa[mi], vb[dt], ot[mi][dt], 0, 0, 0);
  }

  #pragma unroll
  for (int mi = 0; mi < 4; mi++)
    #pragma unroll
    for (int r = 0; r < 4; r++) {
      int i = mi * 16 + hi * 4 + r;
      if (i < NTOK) {
        int row = (int)rowbase + i;
        int tile = row >> 7, rl = row & 127;
        aot[tidx(tile, 6, rl, h * 32 + lo)]      = f2b(ot[mi][0][r] * invl[mi][r]);
        aot[tidx(tile, 6, rl, h * 32 + 16 + lo)] = f2b(ot[mi][1][r] * invl[mi][r]);
      }
    }
}

// ---------------- LN2 -> X2B tiled (round-8, unchanged) ----------------
__global__ void k_ln2(const float* __restrict__ x, const u16* __restrict__ proj,
                      const float* __restrict__ g, const float* __restrict__ b,
                      u16* __restrict__ x2bt) {
  int wid = threadIdx.x >> 6, lane = threadIdx.x & 63;
  int r = blockIdx.x * 4 + wid;
  int tile = r >> 7, rl = r & 127;
  if (r >= M_FULL) {
    u16 z = f2b(0.0f);
    #pragma unroll
    for (int e = 0; e < 6; e++) x2bt[tidx(tile, 6, rl, lane + e * 64)] = z;
    return;
  }
  int bi = r / TOKENS, tk = r % TOKENS;
  const float* xs = x + (size_t)r * DIM;
  float v[6];
  if (tk == 0) {
    #pragma unroll
    for (int e = 0; e < 6; e++) v[e] = xs[lane + e * 64];
  } else {
    int p = tk - 1, hh = p / 56, wp = p % 56;
    int a = (hh + 53) % 56, bw = (wp + 53) % 56;
    int wh = a / 7, ii = a % 7, w2 = bw / 7, jj = bw % 7;
    size_t prow = ((size_t)bi * 64 + wh * 8 + w2) * NTOK + ii * 7 + jj;
    const u16* ps = proj + prow * DIM;
    #pragma unroll
    for (int e = 0; e < 6; e++) v[e] = xs[lane + e * 64] + b2f(ps[lane + e * 64]);
  }
  float s = v[0] + v[1] + v[2] + v[3] + v[4] + v[5];
  #pragma unroll
  for (int m = 1; m < 64; m <<= 1) s += __shfl_xor(s, m);
  float mu = s * (1.0f / 384.0f);
  float q = 0.f;
  #pragma unroll
  for (int e = 0; e < 6; e++) { float d = v[e] - mu; q += d * d; }
  #pragma unroll
  for (int m = 1; m < 64; m <<= 1) q += __shfl_xor(q, m);
  float rstd = rsqrtf(q * (1.0f / 384.0f) + 1e-5f);
  #pragma unroll
  for (int e = 0; e < 6; e++) {
    int c = lane + e * 64;
    x2bt[tidx(tile, 6, rl, c)] = f2b((v[e] - mu) * rstd * g[c] + b[c]);
  }
}

extern "C" void kernel_launch(void* const* d_in, const int* in_sizes, int n_in,
                              void* d_out, int out_size, void* d_ws, size_t ws_size,
                              hipStream_t stream) {
  const float* x      = (const float*)d_in[0];
  const float* n1g    = (const float*)d_in[1];
  const float* n1b    = (const float*)d_in[2];
  const float* qkv_w  = (const float*)d_in[3];
  const float* qkv_b  = (const float*)d_in[4];
  const float* rpb    = (const float*)d_in[5];
  const float* proj_w = (const float*)d_in[6];
  const float* proj_b = (const float*)d_in[7];
  const float* n2g    = (const float*)d_in[8];
  const float* n2b    = (const float*)d_in[9];
  const float* fc1_w  = (const float*)d_in[10];
  const float* fc1_b  = (const float*)d_in[11];
  const float* fc2_w  = (const float*)d_in[12];
  const float* fc2_b  = (const float*)d_in[13];
  float* outp = (float*)d_out;

  auto al = [](size_t v) { return (v + 255) & ~(size_t)255; };
  size_t base = al(884736) + al(294912) + al(1179648) + al(1179648) + al(4608)
              + al(460992) + al((size_t)M_PAD * 768);
  const int cand[3][2] = {{4, 4}, {8, 8}, {16, 16}};
  int NC1 = 16, NC2 = 16;
  for (int ci = 0; ci < 3; ci++) {
    int c1 = cand[ci][0], c2 = cand[ci][1];
    size_t cm = M_ATTN / c1;
    size_t cb_ = (785 + c2 - 1) / c2;
    size_t region = (size_t)M_ATTN * 768;
    size_t fc1b = cb_ * 24 * 8192 * 2;
    if (fc1b > region) region = fc1b;
    size_t tot = base + 2 * al(cm * 768) + al(cm * 2304) + al(region);
    if (tot <= ws_size) { NC1 = c1; NC2 = c2; break; }
  }
  char* p = (char*)d_ws;
  auto take = [&](size_t bytes) { char* r = p; p += al(bytes); return r; };
  u16* wt_qkv  = (u16*)take(884736);
  u16* wt_proj = (u16*)take(294912);
  u16* wt_fc1  = (u16*)take(1179648);
  u16* wt_fc2  = (u16*)take(1179648);
  float* qkvb_s = (float*)take(4608);
  float* ADDt   = (float*)take(460992);
  u16* X2Bt = (u16*)take((size_t)M_PAD * 768);
  int chunkM = M_ATTN / NC1;
  u16* XWt  = (u16*)take((size_t)chunkM * 768);
  u16* QKV  = (u16*)take((size_t)chunkM * 2304);
  u16* AOt  = (u16*)take((size_t)chunkM * 768);
  int cb = (785 + NC2 - 1) / NC2;
  size_t region = (size_t)M_ATTN * 768;
  size_t fc1b = (size_t)cb * 24 * 8192 * 2;
  if (fc1b > region) region = fc1b;
  u16* PROJ = (u16*)take(region);
  u16* FC1t = PROJ;

  k_convert<<<2304, 256, 0, stream>>>(qkv_w, qkv_b, proj_w, fc1_w, fc2_w,
                                      wt_qkv, qkvb_s, wt_proj, wt_fc1, wt_fc2);
  k_addtab<<<451, 256, 0, stream>>>(rpb, ADDt);

  // ---- DIAGNOSTICS: fc1-shaped, 16x repeated K-loop, scratch output (overwritten) ----
  k_diag<1><<<dim3(12, 48), 256, 0, stream>>>(X2Bt, wt_fc1, fc1_b, FC1t, 1536, 6);
  k_diag<2><<<dim3(12, 48), 256, 0, stream>>>(X2Bt, wt_fc1, fc1_b, FC1t, 1536, 6);

  int chunkWin = chunkM / NTOK;
  for (int c = 0; c < NC1; c++) {
    int t0 = c * chunkM;
    k_ln1<<<chunkM / 4, 256, 0, stream>>>(x, n1g, n1b, XWt, t0);
    k_gemm<0><<<dim3(9, chunkM / 128), 256, 0, stream>>>(XWt, wt_qkv, qkvb_s, QKV,
                                                         nullptr, nullptr, 1152, 6, 0);
    k_attn2<<<chunkWin * HEADS / 4, 256, 0, stream>>>(QKV, ADDt, AOt, c * chunkWin);
    k_gemm<0><<<dim3(3, chunkM / 128), 256, 0, stream>>>(AOt, wt_proj, proj_b,
                                                         PROJ + (size_t)t0 * DIM,
                                                         nullptr, nullptr, 384, 6, 0);
  }
  k_ln2<<<M_PAD / 4, 256, 0, stream>>>(x, PROJ, n2g, n2b, X2Bt);
  for (int c = 0; c < NC2; c++) {
    int rb0 = c * cb;
    int nb = 785 - rb0; if (nb > cb) nb = cb; if (nb <= 0) break;
    k_gemm<1><<<dim3(12, nb), 256, 0, stream>>>(X2Bt + (size_t)rb0 * 128 * 384, wt_fc1,
                                                fc1_b, FC1t, nullptr, nullptr, 1536, 6, 0);
    k_gemm<2><<<dim3(3, nb), 256, 0, stream>>>(FC1t, wt_fc2, fc2_b, nullptr, outp, X2Bt,
                                               384, 24, rb0 * 128);
  }
}

// Round 10
// 1013.264 us; speedup vs baseline: 1.2089x; 1.2089x over previous
//
#include <hip/hip_runtime.h>
#include <hip/hip_bf16.h>

#define DIM 384
#define HEADS 12
#define NTOK 49
#define TOKENS 3137
#define M_ATTN 100352   // 32*64*49 window rows
#define M_FULL 100384   // 32*3137 token rows
#define M_PAD2 100608   // 393*256 (GEMM row pad)
#define SCALEQ 0.17677669529663687f

typedef __attribute__((ext_vector_type(8))) short s8v;
typedef __attribute__((ext_vector_type(4))) float f4v;
typedef unsigned short u16;

__device__ __forceinline__ float b2f(int s) {
  union { unsigned u; float f; } c; c.u = ((unsigned)(s & 0xffff)) << 16; return c.f;
}
__device__ __forceinline__ u16 f2b(float f) {
  __hip_bfloat16 h = __float2bfloat16(f);
  return *reinterpret_cast<u16*>(&h);
}
__device__ __forceinline__ void gload16(const void* g, void* l) {
  __builtin_amdgcn_global_load_lds((const __attribute__((address_space(1))) void*)g,
                                   (__attribute__((address_space(3))) void*)l, 16, 0, 0);
}
__device__ __forceinline__ float gelu_f(float val) {
  float u = __builtin_fmaf(0.0713548163f * val, val * val, 1.5957691216f * val);
  return val * __builtin_amdgcn_rcpf(1.0f + __expf(-u));
}
// tiled+pre-swizzled layout [tile128][ks][128 rows][64 cols]
__device__ __forceinline__ size_t tidx(int tile, int KS, int rl, int c) {
  return ((size_t)(tile * KS + (c >> 6)) * 128 + rl) * 64
       + (((((c >> 3) & 7)) ^ (rl & 7)) << 3) + (c & 7);
}

// ---------------- weight convert: tiled+swizzled, N padded to 256-multiples ----------------
__global__ void k_convert(const float* __restrict__ qkv_w, const float* __restrict__ qkv_b,
                          const float* __restrict__ proj_w, const float* __restrict__ proj_b,
                          const float* __restrict__ fc1_w, const float* __restrict__ fc1_b,
                          const float* __restrict__ fc2_w, const float* __restrict__ fc2_b,
                          u16* __restrict__ wt_qkv, float* __restrict__ qkvb_s,
                          u16* __restrict__ wt_proj, float* __restrict__ projb_s,
                          u16* __restrict__ wt_fc1, float* __restrict__ fc1b_s,
                          u16* __restrict__ wt_fc2, float* __restrict__ fc2b_s) {
  int i = blockIdx.x * 256 + threadIdx.x;
  if (i < 1152 * 384) { int n = i / 384, k = i % 384;
    float v = qkv_w[(size_t)k * 1152 + n]; if (n < 384) v *= SCALEQ;
    wt_qkv[tidx(n >> 7, 6, n & 127, k)] = f2b(v); }
  if (i < 128 * 384) { int n = 1152 + i / 384, k = i % 384;
    wt_qkv[tidx(n >> 7, 6, n & 127, k)] = 0; }
  if (i < 1280) qkvb_s[i] = (i < 1152) ? qkv_b[i] * (i < 384 ? SCALEQ : 1.0f) : 0.0f;
  if (i < 384 * 384) { int n = i / 384, k = i % 384;
    wt_proj[tidx(n >> 7, 6, n & 127, k)] = f2b(proj_w[(size_t)k * 384 + n]); }
  if (i < 128 * 384) { int n = 384 + i / 384, k = i % 384;
    wt_proj[tidx(n >> 7, 6, n & 127, k)] = 0; }
  if (i < 512) projb_s[i] = (i < 384) ? proj_b[i] : 0.0f;
  if (i < 1536 * 384) { int n = i / 384, k = i % 384;
    wt_fc1[tidx(n >> 7, 6, n & 127, k)] = f2b(fc1_w[(size_t)k * 1536 + n]); }
  if (i < 1536) fc1b_s[i] = fc1_b[i];
  if (i < 384 * 1536) { int n = i / 1536, k = i % 1536;
    wt_fc2[tidx(n >> 7, 24, n & 127, k)] = f2b(fc2_w[(size_t)k * 384 + n]); }
  if (i < 128 * 1536) { int n = 384 + i / 1536, k = i % 1536;
    wt_fc2[tidx(n >> 7, 24, n & 127, k)] = 0; }
  if (i < 512) fc2b_s[i] = (i < 384) ? fc2_b[i] : 0.0f;
}

// ---------------- ADD table ----------------
__global__ void k_addtab(const float* __restrict__ rpb, float* __restrict__ ADD) {
  int idx = blockIdx.x * 256 + threadIdx.x;
  if (idx >= 4 * HEADS * NTOK * NTOK) return;
  int j = idx % NTOK, t = idx / NTOK;
  int i = t % NTOK; t /= NTOK;
  int h = t % HEADS; int cls = t / HEADS;
  int ii = i / 7, jj = i % 7, ji = j / 7, j2 = j % 7;
  int rpi = (ii - ji + 6) * 13 + (jj - j2 + 6);
  float v = rpb[rpi * HEADS + h];
  int rh = (cls & 2) ? (ii < 4 ? 1 : 2) : 0;
  int rw = (cls & 1) ? (jj < 4 ? 1 : 2) : 0;
  int sh = (cls & 2) ? (ji < 4 ? 1 : 2) : 0;
  int sw = (cls & 1) ? (j2 < 4 ? 1 : 2) : 0;
  if (rh != sh || rw != sw) v -= 100.0f;
  ADD[idx] = v;
}

// ---------------- LN1 -> XW tiled ----------------
__global__ void k_ln1(const float* __restrict__ x, const float* __restrict__ g,
                      const float* __restrict__ b, u16* __restrict__ xwt, int t0) {
  int wid = threadIdx.x >> 6, lane = threadIdx.x & 63;
  int ml = blockIdx.x * 4 + wid;
  int t = t0 + ml;
  int bi = t / 3136, rem = t % 3136;
  int win = rem / NTOK, n = rem % NTOK;
  int wh = win >> 3, ww = win & 7, ii = n / 7, jj = n % 7;
  int h = (wh * 7 + ii + 3) % 56;
  int w = (ww * 7 + jj + 3) % 56;
  const float* src = x + ((size_t)bi * TOKENS + 1 + h * 56 + w) * DIM;
  float v[6];
  #pragma unroll
  for (int e = 0; e < 6; e++) v[e] = src[lane + e * 64];
  float s = v[0] + v[1] + v[2] + v[3] + v[4] + v[5];
  #pragma unroll
  for (int m = 1; m < 64; m <<= 1) s += __shfl_xor(s, m);
  float mu = s * (1.0f / 384.0f);
  float q = 0.f;
  #pragma unroll
  for (int e = 0; e < 6; e++) { float d = v[e] - mu; q += d * d; }
  #pragma unroll
  for (int m = 1; m < 64; m <<= 1) q += __shfl_xor(q, m);
  float rstd = rsqrtf(q * (1.0f / 384.0f) + 1e-5f);
  int tile = ml >> 7, rl = ml & 127;
  #pragma unroll
  for (int e = 0; e < 6; e++) {
    int c = lane + e * 64;
    xwt[tidx(tile, 6, rl, c)] = f2b((v[e] - mu) * rstd * g[c] + b[c]);
  }
}

// ---------------- 256x256 GEMM: 8 waves, wave tile 128x64 (2.67 MFMA/ds_read),
// tiled operands, dbuf + counted vmcnt + T1 remap. Npad = gridDim.x*256.
// MODE 0: bias -> bf16 [row][Nreal] (gcol guard); MODE 1: bias+gelu -> tiled KS=24;
// MODE 2: bias + resid(X2Bt) -> f32 out, row+col guard
template<int MODE>
__global__ __launch_bounds__(512, 2) void k_gemm256(
    const u16* __restrict__ At, const u16* __restrict__ Bt,
    const float* __restrict__ bias, u16* __restrict__ Cb,
    float* __restrict__ outp, const u16* __restrict__ residt,
    int Nreal, int KT, int row_off) {
  __shared__ __align__(16) u16 Ls[2][4][8192];   // 128 KB: [buf][A0,A1,B0,B1][16KB]
  int gx = gridDim.x;
  int lid = blockIdx.y * gx + blockIdx.x;
  int nwg = gx * gridDim.y;
  int q = nwg >> 3, r = nwg & 7;
  int xcd = lid & 7, loc = lid >> 3;
  int tile = (xcd < r ? xcd * (q + 1) : r * (q + 1) + (xcd - r) * q) + loc;
  int m0 = (tile / gx) * 256, n0 = (tile % gx) * 256;
  int tid = threadIdx.x;
  int wid = tid >> 6, lane = tid & 63;
  int lo = lane & 15, hi = lane >> 4;
  int wm = wid >> 2, wn = wid & 3;          // 2M x 4N wave grid, wave tile 128x64
  int cidx = wid >> 1, half = wid & 1;      // staging: wave -> 8KB of chunk cidx
  const u16* gsrc = (cidx < 2)
      ? At + ((size_t)((m0 >> 7) + cidx) * KT) * 8192
      : Bt + ((size_t)((n0 >> 7) + (cidx - 2)) * KT) * 8192;
  gsrc += half * 4096 + lane * 8;
  f4v acc[8][4];
  #pragma unroll
  for (int mi = 0; mi < 8; mi++)
    #pragma unroll
    for (int ni = 0; ni < 4; ni++) acc[mi][ni] = (f4v)(0.0f);
#define STG(buf, kt) do {                                                \
    u16* d_ = &Ls[buf][cidx][half * 4096];                               \
    const u16* s_ = gsrc + (size_t)(kt) * 8192;                          \
    _Pragma("unroll")                                                    \
    for (int g_ = 0; g_ < 8; g_++) gload16(s_ + g_ * 512, d_ + g_ * 512);\
  } while (0)
  STG(0, 0);
  for (int kt = 0; kt < KT; ++kt) {
    int c = kt & 1;
    if (kt + 1 < KT) {
      STG(1 - c, kt + 1);
      asm volatile("s_waitcnt vmcnt(8)" ::: "memory");
    } else {
      asm volatile("s_waitcnt vmcnt(0)" ::: "memory");
    }
    __builtin_amdgcn_s_barrier();           // tile kt visible
    __builtin_amdgcn_sched_barrier(0);
    #pragma unroll
    for (int kk = 0; kk < 2; kk++) {
      int kk4 = kk * 4;
      s8v af[8], bf[4];
      #pragma unroll
      for (int mi = 0; mi < 8; mi++) {
        int rl = mi * 16 + lo;
        af[mi] = *(const s8v*)(&Ls[c][wm][rl * 64 + (((kk4 + hi) ^ (rl & 7)) << 3)]);
      }
      #pragma unroll
      for (int ni = 0; ni < 4; ni++) {
        int rb = (wn & 1) * 64 + ni * 16 + lo;
        bf[ni] = *(const s8v*)(&Ls[c][2 + (wn >> 1)][rb * 64 + (((kk4 + hi) ^ (rb & 7)) << 3)]);
      }
      asm volatile("s_waitcnt lgkmcnt(0)" ::: "memory");
      __builtin_amdgcn_sched_barrier(0);    // rule #18 fence
      if (kk == 1) {                        // all reads of buf c done
        __builtin_amdgcn_s_barrier();
        __builtin_amdgcn_sched_barrier(0);
      }
      __builtin_amdgcn_s_setprio(1);
      #pragma unroll
      for (int mi = 0; mi < 8; mi++)
        #pragma unroll
        for (int ni = 0; ni < 4; ni++)
          acc[mi][ni] = __builtin_amdgcn_mfma_f32_16x16x32_bf16(af[mi], bf[ni], acc[mi][ni], 0, 0, 0);
      __builtin_amdgcn_s_setprio(0);
    }
  }
#undef STG
  #pragma unroll
  for (int mi = 0; mi < 8; mi++)
    #pragma unroll
    for (int ni = 0; ni < 4; ni++) {
      int gcol = n0 + wn * 64 + ni * 16 + lo;
      float bv = bias[gcol];
      #pragma unroll
      for (int r2 = 0; r2 < 4; r2++) {
        int grow = m0 + wm * 128 + mi * 16 + hi * 4 + r2;
        float val = acc[mi][ni][r2] + bv;
        if (MODE == 0) {
          if (gcol < Nreal) Cb[(size_t)grow * Nreal + gcol] = f2b(val);
        } else if (MODE == 1) {
          Cb[tidx(grow >> 7, 24, grow & 127, gcol)] = f2b(gelu_f(val));
        } else {
          int orow = grow + row_off;
          if (orow < M_FULL && gcol < Nreal) {
            float res = b2f(residt[tidx(orow >> 7, 6, orow & 127, gcol)]);
            outp[(size_t)orow * 384 + gcol] = val + res;
          }
        }
      }
    }
}

// ---------------- MFMA attention: one wave per (window, head) ----------------
__global__ __launch_bounds__(256) void k_attn2(const u16* __restrict__ qkv,
                                               const float* __restrict__ ADD,
                                               u16* __restrict__ aot, int win0) {
  __shared__ u16 PT[4][64][76];
  __shared__ u16 VT[4][32][76];
  int wid = threadIdx.x >> 6, lane = threadIdx.x & 63;
  int lo = lane & 15, hi = lane >> 4;
  int gw = blockIdx.x * 4 + wid;
  int win_l = gw / HEADS, h = gw % HEADS;
  int nw = (win0 + win_l) & 63;
  int wh = nw >> 3, ww = nw & 7;
  int cls = ((wh == 7) ? 2 : 0) + ((ww == 7) ? 1 : 0);
  size_t rowbase = (size_t)win_l * NTOK;
  u16 (*pt)[76] = PT[wid];
  u16 (*vt)[76] = VT[wid];

  int rcl[4];
  #pragma unroll
  for (int ti = 0; ti < 4; ti++) {
    int r = ti * 16 + lo;
    rcl[ti] = r < NTOK ? r : NTOK - 1;
  }
  int jrow = lane < NTOK ? lane : NTOK - 1;

  s8v af[4], bf[4];
  #pragma unroll
  for (int ti = 0; ti < 4; ti++) {
    af[ti] = *(const s8v*)(qkv + (rowbase + rcl[ti]) * 1152 + h * 32 + hi * 8);
    bf[ti] = *(const s8v*)(qkv + (rowbase + rcl[ti]) * 1152 + 384 + h * 32 + hi * 8);
  }
  f4v st[4][4];
  #pragma unroll
  for (int mi = 0; mi < 4; mi++)
    #pragma unroll
    for (int ni = 0; ni < 4; ni++)
      st[mi][ni] = __builtin_amdgcn_mfma_f32_16x16x32_bf16(af[mi], bf[ni], (f4v)(0.0f), 0, 0, 0);

  {
    const u16* vsrc = qkv + (rowbase + jrow) * 1152 + 768 + h * 32;
    #pragma unroll
    for (int d0 = 0; d0 < 32; d0 += 8) {
      s8v v = *(const s8v*)(vsrc + d0);
      #pragma unroll
      for (int e = 0; e < 8; e++) vt[d0 + e][lane] = (u16)v[e];
    }
  }

  const float* addb = ADD + ((size_t)cls * HEADS + h) * (NTOK * NTOK);
  #pragma unroll
  for (int mi = 0; mi < 4; mi++)
    #pragma unroll
    for (int ni = 0; ni < 4; ni++) {
      int jj = ni * 16 + lo;
      #pragma unroll
      for (int r = 0; r < 4; r++) {
        int i = mi * 16 + hi * 4 + r;
        if (jj < NTOK) {
          int ic = i < NTOK ? i : NTOK - 1;
          st[mi][ni][r] += addb[ic * NTOK + jj];
        } else st[mi][ni][r] = -1e30f;
      }
    }

  float invl[4][4];
  #pragma unroll
  for (int mi = 0; mi < 4; mi++)
    #pragma unroll
    for (int r = 0; r < 4; r++) {
      float m = fmaxf(fmaxf(st[mi][0][r], st[mi][1][r]), fmaxf(st[mi][2][r], st[mi][3][r]));
      #pragma unroll
      for (int msk = 1; msk < 16; msk <<= 1) m = fmaxf(m, __shfl_xor(m, msk));
      float s = 0.f;
      #pragma unroll
      for (int ni = 0; ni < 4; ni++) {
        float p = __expf(st[mi][ni][r] - m);
        st[mi][ni][r] = p;
        s += p;
      }
      #pragma unroll
      for (int msk = 1; msk < 16; msk <<= 1) s += __shfl_xor(s, msk);
      invl[mi][r] = 1.0f / s;
    }

  #pragma unroll
  for (int ni = 0; ni < 4; ni++)
    #pragma unroll
    for (int mi = 0; mi < 4; mi++) {
      ushort4 pk;
      pk.x = f2b(st[mi][ni][0]); pk.y = f2b(st[mi][ni][1]);
      pk.z = f2b(st[mi][ni][2]); pk.w = f2b(st[mi][ni][3]);
      *(ushort4*)(&pt[ni * 16 + lo][mi * 16 + hi * 4]) = pk;
    }

  f4v ot[4][2];
  #pragma unroll
  for (int mi = 0; mi < 4; mi++)
    #pragma unroll
    for (int dt = 0; dt < 2; dt++) ot[mi][dt] = (f4v)(0.0f);
  #pragma unroll
  for (int kt = 0; kt < 2; kt++) {
    s8v pa[4], vb[2];
    #pragma unroll
    for (int mi = 0; mi < 4; mi++) {
      s8v p;
      #pragma unroll
      for (int e = 0; e < 8; e++) p[e] = (short)pt[kt * 32 + hi * 8 + e][mi * 16 + lo];
      pa[mi] = p;
    }
    #pragma unroll
    for (int dt = 0; dt < 2; dt++) {
      short4 a = *(const short4*)(&vt[dt * 16 + lo][kt * 32 + hi * 8]);
      short4 b = *(const short4*)(&vt[dt * 16 + lo][kt * 32 + hi * 8 + 4]);
      s8v v; v[0] = a.x; v[1] = a.y; v[2] = a.z; v[3] = a.w;
             v[4] = b.x; v[5] = b.y; v[6] = b.z; v[7] = b.w;
      vb[dt] = v;
    }
    #pragma unroll
    for (int mi = 0; mi < 4; mi++)
      #pragma unroll
      for (int dt = 0; dt < 2; dt++)
        ot[mi][dt] = __builtin_amdgcn_mfma_f32_16x16x32_bf16(pa[mi], vb[dt], ot[mi][dt], 0, 0, 0);
  }

  #pragma unroll
  for (int mi = 0; mi < 4; mi++)
    #pragma unroll
    for (int r = 0; r < 4; r++) {
      int i = mi * 16 + hi * 4 + r;
      if (i < NTOK) {
        int row = (int)rowbase + i;
        int tile = row >> 7, rl = row & 127;
        aot[tidx(tile, 6, rl, h * 32 + lo)]      = f2b(ot[mi][0][r] * invl[mi][r]);
        aot[tidx(tile, 6, rl, h * 32 + 16 + lo)] = f2b(ot[mi][1][r] * invl[mi][r]);
      }
    }
}

// ---------------- un-window + roll + residual + LN2 -> X2B tiled (rows padded to M_PAD2) ----
__global__ void k_ln2(const float* __restrict__ x, const u16* __restrict__ proj,
                      const float* __restrict__ g, const float* __restrict__ b,
                      u16* __restrict__ x2bt) {
  int wid = threadIdx.x >> 6, lane = threadIdx.x & 63;
  int r = blockIdx.x * 4 + wid;
  int tile = r >> 7, rl = r & 127;
  if (r >= M_FULL) {
    u16 z = f2b(0.0f);
    #pragma unroll
    for (int e = 0; e < 6; e++) x2bt[tidx(tile, 6, rl, lane + e * 64)] = z;
    return;
  }
  int bi = r / TOKENS, tk = r % TOKENS;
  const float* xs = x + (size_t)r * DIM;
  float v[6];
  if (tk == 0) {
    #pragma unroll
    for (int e = 0; e < 6; e++) v[e] = xs[lane + e * 64];
  } else {
    int p = tk - 1, hh = p / 56, wp = p % 56;
    int a = (hh + 53) % 56, bw = (wp + 53) % 56;
    int wh = a / 7, ii = a % 7, w2 = bw / 7, jj = bw % 7;
    size_t prow = ((size_t)bi * 64 + wh * 8 + w2) * NTOK + ii * 7 + jj;
    const u16* ps = proj + prow * DIM;
    #pragma unroll
    for (int e = 0; e < 6; e++) v[e] = xs[lane + e * 64] + b2f(ps[lane + e * 64]);
  }
  float s = v[0] + v[1] + v[2] + v[3] + v[4] + v[5];
  #pragma unroll
  for (int m = 1; m < 64; m <<= 1) s += __shfl_xor(s, m);
  float mu = s * (1.0f / 384.0f);
  float q = 0.f;
  #pragma unroll
  for (int e = 0; e < 6; e++) { float d = v[e] - mu; q += d * d; }
  #pragma unroll
  for (int m = 1; m < 64; m <<= 1) q += __shfl_xor(q, m);
  float rstd = rsqrtf(q * (1.0f / 384.0f) + 1e-5f);
  #pragma unroll
  for (int e = 0; e < 6; e++) {
    int c = lane + e * 64;
    x2bt[tidx(tile, 6, rl, c)] = f2b((v[e] - mu) * rstd * g[c] + b[c]);
  }
}

extern "C" void kernel_launch(void* const* d_in, const int* in_sizes, int n_in,
                              void* d_out, int out_size, void* d_ws, size_t ws_size,
                              hipStream_t stream) {
  const float* x      = (const float*)d_in[0];
  const float* n1g    = (const float*)d_in[1];
  const float* n1b    = (const float*)d_in[2];
  const float* qkv_w  = (const float*)d_in[3];
  const float* qkv_b  = (const float*)d_in[4];
  const float* rpb    = (const float*)d_in[5];
  const float* proj_w = (const float*)d_in[6];
  const float* proj_b = (const float*)d_in[7];
  const float* n2g    = (const float*)d_in[8];
  const float* n2b    = (const float*)d_in[9];
  const float* fc1_w  = (const float*)d_in[10];
  const float* fc1_b  = (const float*)d_in[11];
  const float* fc2_w  = (const float*)d_in[12];
  const float* fc2_b  = (const float*)d_in[13];
  float* outp = (float*)d_out;

  auto al = [](size_t v) { return (v + 255) & ~(size_t)255; };
  // fixed: weights (padded) + biases + ADD + X2Bt
  size_t base = al(983040) + al(393216) + al(1179648) + al(1572864)
              + al(5120) + al(2048) + al(6144) + al(2048)
              + al(460992) + al((size_t)M_PAD2 * 768);
  const int cand[4][2] = {{4, 4}, {4, 8}, {8, 8}, {8, 16}};
  int NC1 = 8, NC2 = 16;
  for (int ci = 0; ci < 4; ci++) {
    int c1 = cand[ci][0], c2 = cand[ci][1];
    size_t cm = M_ATTN / c1;                       // divisible by 256 for c1 in {4,8}
    int ct = (393 + c2 - 1) / c2;                  // 256-row tiles per MLP chunk
    size_t region = (size_t)M_ATTN * 768;          // PROJ (row-major)
    size_t fc1b = (size_t)ct * 786432;             // FC1 tiled: ct*2 tiles *24*16KB
    if (fc1b > region) region = fc1b;
    size_t tot = base + 2 * al(cm * 768) + al(cm * 2304) + al(region);
    if (tot <= ws_size) { NC1 = c1; NC2 = c2; break; }
  }
  char* p = (char*)d_ws;
  auto take = [&](size_t bytes) { char* r = p; p += al(bytes); return r; };
  u16* wt_qkv  = (u16*)take(983040);
  u16* wt_proj = (u16*)take(393216);
  u16* wt_fc1  = (u16*)take(1179648);
  u16* wt_fc2  = (u16*)take(1572864);
  float* qkvb_s = (float*)take(5120);
  float* projb_s = (float*)take(2048);
  float* fc1b_s = (float*)take(6144);
  float* fc2b_s = (float*)take(2048);
  float* ADDt   = (float*)take(460992);
  u16* X2Bt = (u16*)take((size_t)M_PAD2 * 768);
  int chunkM = M_ATTN / NC1;
  u16* XWt  = (u16*)take((size_t)chunkM * 768);
  u16* QKV  = (u16*)take((size_t)chunkM * 2304);
  u16* AOt  = (u16*)take((size_t)chunkM * 768);
  int ct = (393 + NC2 - 1) / NC2;
  size_t region = (size_t)M_ATTN * 768;
  size_t fc1b = (size_t)ct * 786432;
  if (fc1b > region) region = fc1b;
  u16* PROJ = (u16*)take(region);      // aliased: PROJ dead before FC1 written
  u16* FC1t = PROJ;

  k_convert<<<2304, 256, 0, stream>>>(qkv_w, qkv_b, proj_w, proj_b, fc1_w, fc1_b,
                                      fc2_w, fc2_b, wt_qkv, qkvb_s, wt_proj, projb_s,
                                      wt_fc1, fc1b_s, wt_fc2, fc2b_s);
  k_addtab<<<451, 256, 0, stream>>>(rpb, ADDt);
  int chunkWin = chunkM / NTOK;
  int mt1 = chunkM / 256;
  for (int c = 0; c < NC1; c++) {
    int t0 = c * chunkM;
    k_ln1<<<chunkM / 4, 256, 0, stream>>>(x, n1g, n1b, XWt, t0);
    k_gemm256<0><<<dim3(5, mt1), 512, 0, stream>>>(XWt, wt_qkv, qkvb_s, QKV,
                                                   nullptr, nullptr, 1152, 6, 0);
    k_attn2<<<chunkWin * HEADS / 4, 256, 0, stream>>>(QKV, ADDt, AOt, c * chunkWin);
    k_gemm256<0><<<dim3(2, mt1), 512, 0, stream>>>(AOt, wt_proj, projb_s,
                                                   PROJ + (size_t)t0 * DIM,
                                                   nullptr, nullptr, 384, 6, 0);
  }
  k_ln2<<<M_PAD2 / 4, 256, 0, stream>>>(x, PROJ, n2g, n2b, X2Bt);
  for (int c = 0; c < NC2; c++) {
    int tb0 = c * ct;
    int nt = 393 - tb0; if (nt > ct) nt = ct; if (nt <= 0) break;
    // fc1: A = X2Bt chunk (tiled KS=6), out = FC1t (local tiled KS=24)
    k_gemm256<1><<<dim3(6, nt), 512, 0, stream>>>(
        X2Bt + (size_t)(tb0 * 2) * 6 * 8192, wt_fc1, fc1b_s, FC1t,
        nullptr, nullptr, 1536, 6, 0);
    // fc2: A = FC1t (tiled KS=24), + resid from X2Bt (global tiles) -> f32 out
    k_gemm256<2><<<dim3(2, nt), 512, 0, stream>>>(
        FC1t, wt_fc2, fc2b_s, nullptr, outp, X2Bt, 384, 24, tb0 * 256);
  }
}